// Round 8
// baseline (115.516 us; speedup 1.0000x reference)
//
#include <hip/hip_runtime.h>
#include <math.h>

#define DMODEL 512
#define NSEQ 2048
#define NHEAD 8
#define DK 64
#define DV 64
#define MFEAT 266
#define MPAD 288        // padded feature dim for bf16 MFMA (zero tail), mult of 32
#define NT 32           // number of chunks (chunk = 64)
#define LN_EPS 1e-6f
#define KERNEL_EPS 1e-4f
#define NORM_STAB 1e-6f
#define SCALE 0.21022410381342863f  // 512^-0.25

typedef __attribute__((ext_vector_type(8))) short short8;
typedef __attribute__((ext_vector_type(4))) short sv4;
typedef __attribute__((ext_vector_type(4))) float f32x4;

__device__ inline short f2bf(float f) {
    unsigned u = __builtin_bit_cast(unsigned, f);
    unsigned r = (u + 0x7fff + ((u >> 16) & 1)) >> 16;
    return (short)r;
}
__device__ inline float bf2f(short s) {
    unsigned u = ((unsigned)(unsigned short)s) << 16;
    return __builtin_bit_cast(float, u);
}

// ---------------- LN stats: per-row mu, rstd (one wave per row) ----------------
__global__ __launch_bounds__(256) void ln_stats_kernel(const float* __restrict__ q,
                                                       float* __restrict__ mu,
                                                       float* __restrict__ rstd) {
    int row = blockIdx.x * 4 + (threadIdx.x >> 6);
    int lane = threadIdx.x & 63;
    const float* x = q + (size_t)row * DMODEL + lane * 8;
    f32x4 a = *(const f32x4*)x;
    f32x4 b = *(const f32x4*)(x + 4);
    float s = a[0] + a[1] + a[2] + a[3] + b[0] + b[1] + b[2] + b[3];
    float ss = a[0]*a[0] + a[1]*a[1] + a[2]*a[2] + a[3]*a[3]
             + b[0]*b[0] + b[1]*b[1] + b[2]*b[2] + b[3]*b[3];
    for (int o = 32; o > 0; o >>= 1) {
        s += __shfl_down(s, o);
        ss += __shfl_down(ss, o);
    }
    if (lane == 0) {
        float m = s / (float)DMODEL;
        float var = ss / (float)DMODEL - m * m;
        mu[row] = m;
        rstd[row] = rsqrtf(var + LN_EPS);
    }
}

// ---------------- fused QKV bf16 MFMA GEMM; z=0 applies LN; z=1 emits h_k; bf16 outputs ----------------
__global__ __launch_bounds__(256) void qkv_kernel(const float* __restrict__ qx,
                                                  const float* __restrict__ kx,
                                                  const float* __restrict__ vx,
                                                  const float* __restrict__ Wq,
                                                  const float* __restrict__ Wk,
                                                  const float* __restrict__ Wv,
                                                  const float* __restrict__ mu,
                                                  const float* __restrict__ rstd,
                                                  const float* __restrict__ gamma,
                                                  const float* __restrict__ beta,
                                                  short* __restrict__ qh,
                                                  short* __restrict__ kh,
                                                  short* __restrict__ vh,
                                                  float* __restrict__ hk,
                                                  float* __restrict__ partial) {
    int z = blockIdx.z;
    const float* A = (z == 0) ? qx : (z == 1) ? kx : vx;
    const float* B = (z == 0) ? Wq : (z == 1) ? Wk : Wv;
    short* C = (z == 0) ? qh : (z == 1) ? kh : vh;
    float scale = (z == 2) ? 1.f : SCALE;

    __shared__ short As[64][40];
    __shared__ short Bs[64][40];
    int bm = blockIdx.y * 64, bn = blockIdx.x * 64;
    int tid = threadIdx.x;
    int wid = tid >> 6, lane = tid & 63;
    f32x4 acc[4] = {f32x4{0,0,0,0}, f32x4{0,0,0,0}, f32x4{0,0,0,0}, f32x4{0,0,0,0}};
    int ar = tid >> 2, akq = tid & 3;
    int bkk = tid >> 3, bng = tid & 7;
    float lnm = 0.f, lnr = 0.f;
    if (z == 0) { lnm = mu[bm + ar]; lnr = rstd[bm + ar]; }
    for (int k0 = 0; k0 < DMODEL; k0 += 32) {
        {
            const float* src = A + (size_t)(bm + ar) * DMODEL + k0 + akq * 8;
            f32x4 v0 = *(const f32x4*)src;
            f32x4 v1 = *(const f32x4*)(src + 4);
            short8 sv;
            if (z == 0) {
                f32x4 g0 = *(const f32x4*)&gamma[k0 + akq * 8];
                f32x4 g1 = *(const f32x4*)&gamma[k0 + akq * 8 + 4];
                f32x4 bb0 = *(const f32x4*)&beta[k0 + akq * 8];
                f32x4 bb1 = *(const f32x4*)&beta[k0 + akq * 8 + 4];
                for (int j = 0; j < 4; ++j) {
                    sv[j] = f2bf((v0[j] - lnm) * lnr * g0[j] + bb0[j]);
                    sv[4 + j] = f2bf((v1[j] - lnm) * lnr * g1[j] + bb1[j]);
                }
            } else {
                for (int j = 0; j < 4; ++j) { sv[j] = f2bf(v0[j]); sv[4 + j] = f2bf(v1[j]); }
            }
            *(short8*)&As[ar][akq * 8] = sv;
        }
        {
            const float* src = B + (size_t)(k0 + bkk) * DMODEL + bn + bng * 8;
            f32x4 v0 = *(const f32x4*)src;
            f32x4 v1 = *(const f32x4*)(src + 4);
            for (int j = 0; j < 4; ++j) {
                Bs[bng * 8 + j][bkk] = f2bf(v0[j] * scale);
                Bs[bng * 8 + 4 + j][bkk] = f2bf(v1[j] * scale);
            }
        }
        __syncthreads();
        int row = wid * 16 + (lane & 15);
        int koff = (lane >> 4) * 8;
        short8 a = *(const short8*)&As[row][koff];
        for (int nf = 0; nf < 4; ++nf) {
            int col = nf * 16 + (lane & 15);
            short8 b = *(const short8*)&Bs[col][koff];
            acc[nf] = __builtin_amdgcn_mfma_f32_16x16x32_bf16(a, b, acc[nf], 0, 0, 0);
        }
        __syncthreads();
    }
    for (int nf = 0; nf < 4; ++nf) {
        int col = bn + nf * 16 + (lane & 15);
        for (int j = 0; j < 4; ++j) {
            int row = bm + wid * 16 + (lane >> 4) * 4 + j;
            C[(size_t)row * DMODEL + col] = f2bf(acc[nf][j]);
        }
    }
    if (z == 1) {
        __shared__ float bmax[4];
        float hvmax = -1e30f;
        for (int j = 0; j < 4; ++j) {
            float ss = 0.f;
            for (int nf = 0; nf < 4; ++nf) ss += acc[nf][j] * acc[nf][j];
            for (int o = 1; o < 16; o <<= 1) ss += __shfl_xor(ss, o);
            float hv = -0.5f * ss;
            int row = bm + wid * 16 + (lane >> 4) * 4 + j;
            if ((lane & 15) == 0) hk[(size_t)blockIdx.x * NSEQ + row] = hv;
            hvmax = fmaxf(hvmax, hv);
        }
        for (int o = 32; o > 0; o >>= 1) hvmax = fmaxf(hvmax, __shfl_down(hvmax, o));
        if (lane == 0) bmax[wid] = hvmax;
        __syncthreads();
        if (tid == 0)
            partial[blockIdx.y * 8 + blockIdx.x] =
                fmaxf(fmaxf(bmax[0], bmax[1]), fmaxf(bmax[2], bmax[3]));
    }
}

// ---------------- MFMA random feature maps -> bf16 [h][n][MPAD]; grid (nt, h, isQ) ----------------
__global__ __launch_bounds__(256) void feat_kernel(const short* __restrict__ qh,
                                                   const short* __restrict__ kh,
                                                   const float* __restrict__ rf,
                                                   const float* __restrict__ hkv,
                                                   const float* __restrict__ partial,
                                                   short* __restrict__ qp,
                                                   short* __restrict__ kp) {
    int nt = blockIdx.x, h = blockIdx.y, isQ = blockIdx.z;
    int n0 = nt * 64;
    int tid = threadIdx.x, w = tid >> 6, l = tid & 63;
    __shared__ short U[288 * 72];   // union: rfb[288][72] then kp_lds[64][296]
    __shared__ short Xs[64][72];
    __shared__ float red[4];

    // inline kstab reduce (partial[256] written by qkv z=1)
    float pm = partial[tid];
    for (int o = 32; o > 0; o >>= 1) pm = fmaxf(pm, __shfl_down(pm, o));
    if (l == 0) red[w] = pm;

    // stage rf -> bf16 rfb[m][d] (zero for m>=MFEAT)
    short (*rfb)[72] = (short(*)[72])U;
    for (int lp = 0; lp < 5; ++lp) {
        int c = tid + lp * 256;
        if (c < 288 * 4) {
            int m = c >> 2, dq = (c & 3) * 16;
            short8 s0, s1;
            if (m < MFEAT) {
                f32x4 v0 = *(const f32x4*)&rf[(size_t)m * DK + dq];
                f32x4 v1 = *(const f32x4*)&rf[(size_t)m * DK + dq + 4];
                f32x4 v2 = *(const f32x4*)&rf[(size_t)m * DK + dq + 8];
                f32x4 v3 = *(const f32x4*)&rf[(size_t)m * DK + dq + 12];
                for (int j = 0; j < 4; ++j) {
                    s0[j] = f2bf(v0[j]); s0[4 + j] = f2bf(v1[j]);
                    s1[j] = f2bf(v2[j]); s1[4 + j] = f2bf(v3[j]);
                }
            } else {
                for (int j = 0; j < 8; ++j) { s0[j] = 0; s1[j] = 0; }
            }
            *(short8*)&rfb[m][dq] = s0;
            *(short8*)&rfb[m][dq + 8] = s1;
        }
    }
    // stage X chunk (bf16) -> Xs[n][d]
    const short* xh = isQ ? qh : kh;
    {
        int n = tid >> 2, dq = (tid & 3) * 16;
        const short* src = xh + (size_t)(n0 + n) * DMODEL + h * DK + dq;
        *(short8*)&Xs[n][dq] = *(const short8*)src;
        *(short8*)&Xs[n][dq + 8] = *(const short8*)(src + 8);
    }
    __syncthreads();
    float ks = fmaxf(fmaxf(red[0], red[1]), fmaxf(red[2], red[3]));

    // proj MFMA: C[m][n] = sum_d rfb[m][d] * Xs[n][d]; wave w owns n-tile w
    int fr = l & 15, fq = (l >> 4) * 8;
    short8 xb0 = *(const short8*)&Xs[w * 16 + fr][fq];
    short8 xb1 = *(const short8*)&Xs[w * 16 + fr][32 + fq];
    f32x4 acc[18];
#pragma unroll
    for (int tr = 0; tr < 18; ++tr) acc[tr] = f32x4{0, 0, 0, 0};
#pragma unroll
    for (int tr = 0; tr < 18; ++tr) {
        short8 a0 = *(const short8*)&rfb[tr * 16 + fr][fq];
        short8 a1 = *(const short8*)&rfb[tr * 16 + fr][32 + fq];
        acc[tr] = __builtin_amdgcn_mfma_f32_16x16x32_bf16(a0, xb0, acc[tr], 0, 0, 0);
        acc[tr] = __builtin_amdgcn_mfma_f32_16x16x32_bf16(a1, xb1, acc[tr], 0, 0, 0);
    }
    __syncthreads();  // all waves done reading rfb; U becomes kp_lds

    short (*kpl)[296] = (short(*)[296])U;
    int n_loc = w * 16 + fr;
    int n = n0 + n_loc;
    const float cnorm = 0.06131393394849658f;  // 266^-0.5
    float hval = isQ ? 0.f : (hkv[(size_t)h * NSEQ + n] - ks);
#pragma unroll
    for (int tr = 0; tr < 18; ++tr) {
        sv4 o;
        for (int j = 0; j < 4; ++j) {
            int m = tr * 16 + (l >> 4) * 4 + j;
            float val = (m < MFEAT) ? cnorm * (expf(acc[tr][j] + hval) + KERNEL_EPS) : 0.f;
            o[j] = f2bf(val);
        }
        *(sv4*)&kpl[n_loc][tr * 16 + (l >> 4) * 4] = o;
    }
    __syncthreads();
    // coalesced copy kp_lds rows -> HBM
    short* outp = isQ ? qp : kp;
    for (int lp = 0; lp < 9; ++lp) {
        int c = tid + lp * 256;      // 64 rows * 36 chunks
        int nn = c / 36, c8 = c % 36;
        short8 v = *(const short8*)&kpl[nn][c8 * 8];
        *(short8*)&outp[((size_t)h * NSEQ + n0 + nn) * MPAD + c8 * 8] = v;
    }
}

// ---------------- phase A: per-chunk sums -> bf16 KVc[(h,t,dv)][m], fp32 Ks[(h,t)][m] ----------------
__global__ __launch_bounds__(256) void chunksum_kernel(const short* __restrict__ kp,
                                                       const short* __restrict__ vh,
                                                       short* __restrict__ KVc,
                                                       float* __restrict__ Ks) {
    int mt = blockIdx.x, t = blockIdx.y, h = blockIdx.z;
    int m0 = mt * 64;
    int tid = threadIdx.x;
    int tx = tid & 15, ty = tid >> 4;
    __shared__ float Kl[64][68];  // [i][mloc]
    __shared__ float Vl[64][68];  // [i][dv]
    for (int l = 0; l < 2; ++l) {
        int idx = tid + l * 256;
        int i = idx >> 3, c8 = idx & 7;
        int m = m0 + c8 * 8;
        float vals[8] = {0.f, 0.f, 0.f, 0.f, 0.f, 0.f, 0.f, 0.f};
        if (m + 7 < MPAD) {
            short8 sv = *(const short8*)&kp[((size_t)h * NSEQ + t * 64 + i) * MPAD + m];
            for (int j = 0; j < 8; ++j) vals[j] = bf2f(sv[j]);
        }
        for (int j = 0; j < 8; ++j) Kl[i][c8 * 8 + j] = vals[j];
        short8 vv = *(const short8*)&vh[(size_t)(t * 64 + i) * DMODEL + h * DV + c8 * 8];
        for (int j = 0; j < 8; ++j) Vl[i][c8 * 8 + j] = bf2f(vv[j]);
    }
    __syncthreads();
    float acc[4][4] = {};
#pragma unroll 4
    for (int i = 0; i < 64; ++i) {
        f32x4 a = *(const f32x4*)&Kl[i][ty * 4];
        f32x4 b = *(const f32x4*)&Vl[i][tx * 4];
        for (int r = 0; r < 4; ++r)
            for (int c = 0; c < 4; ++c) acc[r][c] += a[r] * b[c];
    }
    int m = m0 + ty * 4;
    if (m < MPAD) {
        for (int c = 0; c < 4; ++c) {
            int dv = tx * 4 + c;
            sv4 o;
            for (int r = 0; r < 4; ++r) o[r] = f2bf(acc[r][c]);
            *(sv4*)&KVc[(((size_t)h * NT + t) * DV + dv) * MPAD + m] = o;
        }
    }
    if (tid < 64) {
        int ms = m0 + tid;
        if (ms < MPAD) {
            float s = 0.f;
#pragma unroll 8
            for (int i = 0; i < 64; ++i) s += Kl[i][tid];
            Ks[((size_t)h * NT + t) * MPAD + ms] = s;
        }
    }
}

// ---------------- fused exclusive chunk-scans (bf16 KVc -> bf16 S^T, Ks -> prefix + Ktot) ----------------
__global__ void scan_kernel(const short* __restrict__ KVc, short* __restrict__ KVbT,
                            float* __restrict__ Ks, float* __restrict__ Ktot) {
    int idx = blockIdx.x * 256 + threadIdx.x;
    const int NKV = NHEAD * DV * MPAD;       // 147456
    if (idx < NKV) {
        int h = idx / (DV * MPAD);
        int rem = idx % (DV * MPAD);
        size_t base = (size_t)h * NT * DV * MPAD + rem;
        float run = 0.f;
        for (int t = 0; t < NT; ++t) {
            size_t o = base + (size_t)t * DV * MPAD;
            KVbT[o] = f2bf(run);
            run += bf2f(KVc[o]);
        }
    } else {
        int j = idx - NKV;
        if (j < NHEAD * MPAD) {
            int h = j / MPAD, m = j % MPAD;
            size_t base = (size_t)h * NT * MPAD + m;
            float run = 0.f;
            for (int t = 0; t < NT; ++t) {
                size_t o = base + (size_t)t * MPAD;
                float v = Ks[o];
                Ks[o] = run;
                run += v;
            }
            Ktot[(size_t)h * MPAD + m] = run;
        }
    }
}

// ---------------- phase C: MFMA intra+inter+denominators; grid (t, h, z=row-half) ----------------
__global__ __launch_bounds__(256) void phasec_kernel(const short* __restrict__ qp,
                                                     const short* __restrict__ kp,
                                                     const short* __restrict__ vh,
                                                     const short* __restrict__ KVbT,
                                                     const float* __restrict__ Ks,
                                                     const float* __restrict__ Ktot,
                                                     float* __restrict__ attn) {
    int t = blockIdx.x, h = blockIdx.y, z = blockIdx.z;
    __shared__ short Buf[64][296];   // Kp (QK^T phase) then St (inter phase)
    __shared__ short Vt[64][72];     // [dv][key]
    __shared__ short Am[32][72];     // masked A (local rows), bf16
    __shared__ float Ksp[MPAD], Ktp[MPAD];
    __shared__ float fscale_s[32];
    int tid = threadIdx.x;
    int w = tid >> 6, l = tid & 63;
    int rt = w >> 1, ch = w & 1;     // row-tile 0..1, col-half 0..1
    int fr = l & 15, fq = (l >> 4) * 8;
    int nkeys = z ? 64 : 32;
    const short* qpb = qp + ((size_t)h * NSEQ + (size_t)t * 64 + z * 32) * MPAD;
    const short* kpb = kp + ((size_t)h * NSEQ + (size_t)t * 64) * MPAD;
    const short* stb = KVbT + ((size_t)h * NT + t) * DV * MPAD;

    // Q fragments: local rows rt*16 + fr
    short8 qf[9];
#pragma unroll
    for (int ks = 0; ks < 9; ++ks)
        qf[ks] = *(const short8*)&qpb[(size_t)(rt * 16 + fr) * MPAD + ks * 32 + fq];

    // stage Kp rows [0, nkeys)
    for (int c = tid; c < nkeys * 36; c += 256) {
        int r = c / 36, c8 = c % 36;
        *(short8*)&Buf[r][c8 * 8] = *(const short8*)&kpb[(size_t)r * MPAD + c8 * 8];
    }
    // stage Vt[dv][key] (bf16 copy)
    {
        int dv = tid >> 2, i0 = (tid & 3) * 16;
        for (int it = 0; it < 16; ++it) {
            int i = i0 + it;
            if (i < nkeys)
                Vt[dv][i] = vh[(size_t)(t * 64 + i) * DMODEL + h * DV + dv];
        }
    }
    for (int idx = tid; idx < MPAD; idx += 256) {
        Ksp[idx] = Ks[((size_t)h * NT + t) * MPAD + idx];
        Ktp[idx] = Ktot[(size_t)h * MPAD + idx];
    }
    __syncthreads();

    f32x4 accA[2] = {f32x4{0,0,0,0}, f32x4{0,0,0,0}};
    f32x4 accO[2] = {f32x4{0,0,0,0}, f32x4{0,0,0,0}};
    // QK^T (z=0: only ch==0 waves — cols 32..63 are fully masked)
    if (z || ch == 0) {
#pragma unroll 3
        for (int ks = 0; ks < 9; ++ks) {
            int ko = ks * 32 + fq;
            for (int nf = 0; nf < 2; ++nf) {
                short8 bk = *(const short8*)&Buf[ch * 32 + nf * 16 + fr][ko];
                accA[nf] = __builtin_amdgcn_mfma_f32_16x16x32_bf16(qf[ks], bk, accA[nf], 0, 0, 0);
            }
        }
    }
    __syncthreads();
    // restage Buf with St (full 64 dv rows); write masked Am
    for (int c = tid; c < 64 * 36; c += 256) {
        int r = c / 36, c8 = c % 36;
        *(short8*)&Buf[r][c8 * 8] = *(const short8*)&stb[(size_t)r * MPAD + c8 * 8];
    }
    if (z || ch == 0) {
        for (int nf = 0; nf < 2; ++nf) {
            int key = ch * 32 + nf * 16 + fr;
            for (int j = 0; j < 4; ++j) {
                int row = rt * 16 + (l >> 4) * 4 + j;
                Am[row][key] = (key <= z * 32 + row) ? f2bf(accA[nf][j]) : (short)0;
            }
        }
    }
    __syncthreads();
    // inter: accO += Qp . S (all waves, 2 dv-frags each)
#pragma unroll 3
    for (int ks = 0; ks < 9; ++ks) {
        int ko = ks * 32 + fq;
        for (int nf = 0; nf < 2; ++nf) {
            short8 bs = *(const short8*)&Buf[ch * 32 + nf * 16 + fr][ko];
            accO[nf] = __builtin_amdgcn_mfma_f32_16x16x32_bf16(qf[ks], bs, accO[nf], 0, 0, 0);
        }
    }
    // intra: accO += Am_masked . V  (K-dim = nkeys)
    {
        int nks = z ? 2 : 1;
        for (int ks = 0; ks < nks; ++ks) {
            int ko = ks * 32 + fq;
            short8 a = *(const short8*)&Am[rt * 16 + fr][ko];
            for (int nf = 0; nf < 2; ++nf) {
                short8 b = *(const short8*)&Vt[ch * 32 + nf * 16 + fr][ko];
                accO[nf] = __builtin_amdgcn_mfma_f32_16x16x32_bf16(a, b, accO[nf], 0, 0, 0);
            }
        }
    }
    // denominators: 8 threads per local row
    int di = tid >> 3, dp = tid & 7;
    float dc = 0.f, df = 0.f;
    if (dp * 8 < nkeys) {
        short8 s0 = *(const short8*)&Am[di][dp * 8];
        for (int j2 = 0; j2 < 8; ++j2) dc += bf2f(s0[j2]);
    }
#pragma unroll
    for (int c = 0; c < 9; ++c) {
        int m = dp * 36 + c * 4;
        sv4 qv = *(const sv4*)&qpb[(size_t)di * MPAD + m];
        for (int j2 = 0; j2 < 4; ++j2) {
            float qq = bf2f(qv[j2]);
            dc += qq * Ksp[m + j2];
            df += qq * Ktp[m + j2];
        }
    }
    dc += __shfl_xor(dc, 1); dc += __shfl_xor(dc, 2); dc += __shfl_xor(dc, 4);
    df += __shfl_xor(df, 1); df += __shfl_xor(df, 2); df += __shfl_xor(df, 4);
    if (dp == 0) {
        float dst = df;
        if (fabsf(dst) <= NORM_STAB) dst += 2.f * NORM_STAB;
        fscale_s[di] = (1.f / dc) / dst;
    }
    __syncthreads();
    // epilogue
    for (int nf = 0; nf < 2; ++nf) {
        int col = ch * 32 + nf * 16 + fr;
        for (int j = 0; j < 4; ++j) {
            int row = rt * 16 + (l >> 4) * 4 + j;
            attn[((size_t)t * 64 + z * 32 + row) * DMODEL + h * DV + col] =
                accO[nf][j] * fscale_s[row];
        }
    }
}

// ---------------- final GEMM with bias + residual ----------------
__global__ __launch_bounds__(256) void fgemm_kernel(const float* __restrict__ A,
                                                    const float* __restrict__ B,
                                                    float* __restrict__ C,
                                                    const float* __restrict__ bias,
                                                    const float* __restrict__ residual) {
    __shared__ short As[64][40];
    __shared__ short Bs[64][40];
    int bm = blockIdx.y * 64, bn = blockIdx.x * 64;
    int tid = threadIdx.x;
    int wid = tid >> 6, lane = tid & 63;
    f32x4 acc[4] = {f32x4{0,0,0,0}, f32x4{0,0,0,0}, f32x4{0,0,0,0}, f32x4{0,0,0,0}};
    int ar = tid >> 2, akq = tid & 3;
    int bkk = tid >> 3, bng = tid & 7;
    for (int k0 = 0; k0 < DMODEL; k0 += 32) {
        {
            const float* src = A + (size_t)(bm + ar) * DMODEL + k0 + akq * 8;
            f32x4 v0 = *(const f32x4*)src;
            f32x4 v1 = *(const f32x4*)(src + 4);
            short8 sv;
            for (int j = 0; j < 4; ++j) { sv[j] = f2bf(v0[j]); sv[4 + j] = f2bf(v1[j]); }
            *(short8*)&As[ar][akq * 8] = sv;
        }
        {
            const float* src = B + (size_t)(k0 + bkk) * DMODEL + bn + bng * 8;
            f32x4 v0 = *(const f32x4*)src;
            f32x4 v1 = *(const f32x4*)(src + 4);
            for (int j = 0; j < 4; ++j) {
                Bs[bng * 8 + j][bkk] = f2bf(v0[j]);
                Bs[bng * 8 + 4 + j][bkk] = f2bf(v1[j]);
            }
        }
        __syncthreads();
        int row = wid * 16 + (lane & 15);
        int koff = (lane >> 4) * 8;
        short8 a = *(const short8*)&As[row][koff];
        for (int nf = 0; nf < 4; ++nf) {
            int col = nf * 16 + (lane & 15);
            short8 b = *(const short8*)&Bs[col][koff];
            acc[nf] = __builtin_amdgcn_mfma_f32_16x16x32_bf16(a, b, acc[nf], 0, 0, 0);
        }
        __syncthreads();
    }
    for (int nf = 0; nf < 4; ++nf) {
        int col = bn + nf * 16 + (lane & 15);
        for (int j = 0; j < 4; ++j) {
            int row = bm + wid * 16 + (lane >> 4) * 4 + j;
            C[(size_t)row * DMODEL + col] =
                acc[nf][j] + bias[col] + residual[(size_t)row * DMODEL + col];
        }
    }
}

extern "C" void kernel_launch(void* const* d_in, const int* in_sizes, int n_in,
                              void* d_out, int out_size, void* d_ws, size_t ws_size,
                              hipStream_t stream) {
    const float* q = (const float*)d_in[0];
    const float* k = (const float*)d_in[1];
    const float* v = (const float*)d_in[2];
    const float* Wq = (const float*)d_in[3];
    const float* Wk = (const float*)d_in[4];
    const float* Wv = (const float*)d_in[5];
    const float* Wfc = (const float*)d_in[6];
    const float* bfc = (const float*)d_in[7];
    const float* gamma = (const float*)d_in[8];
    const float* beta = (const float*)d_in[9];
    const float* rf = (const float*)d_in[10];
    float* out = (float*)d_out;

    float* ws = (float*)d_ws;
    float* attn = ws;                                      // fp32 2048*512
    short* qh = (short*)(attn + (size_t)NSEQ * DMODEL);    // bf16 2048*512
    short* kh = qh + (size_t)NSEQ * DMODEL;                // bf16 2048*512
    short* vhb = kh + (size_t)NSEQ * DMODEL;               // bf16 2048*512
    short* qp = vhb + (size_t)NSEQ * DMODEL;               // bf16 8*2048*288
    short* kp = qp + (size_t)NHEAD * NSEQ * MPAD;          // bf16 8*2048*288
    short* KVc = kp + (size_t)NHEAD * NSEQ * MPAD;         // bf16 8*32*64*288
    short* KVbT = KVc + (size_t)NHEAD * NT * DV * MPAD;    // bf16 8*32*64*288
    float* Ks = (float*)(KVbT + (size_t)NHEAD * NT * DV * MPAD);   // fp32 8*32*288
    float* Ktot = Ks + (size_t)NHEAD * NT * MPAD;          // 8*288
    float* hk = Ktot + (size_t)NHEAD * MPAD;               // 8*2048
    float* partial = hk + (size_t)NHEAD * NSEQ;            // 256
    float* mu = partial + 256;                             // 2048
    float* rstd = mu + NSEQ;                               // 2048

    ln_stats_kernel<<<NSEQ / 4, 256, 0, stream>>>(q, mu, rstd);
    dim3 gq(DMODEL / 64, NSEQ / 64, 3);
    qkv_kernel<<<gq, 256, 0, stream>>>(q, k, v, Wq, Wk, Wv, mu, rstd, gamma, beta,
                                       qh, kh, vhb, hk, partial);
    dim3 gf(NT, NHEAD, 2);
    feat_kernel<<<gf, 256, 0, stream>>>(qh, kh, rf, hk, partial, qp, kp);
    dim3 ga(5, NT, NHEAD);
    chunksum_kernel<<<ga, 256, 0, stream>>>(kp, vhb, KVc, Ks);
    int scan_threads = NHEAD * DV * MPAD + NHEAD * MPAD;
    scan_kernel<<<(scan_threads + 255) / 256, 256, 0, stream>>>(KVc, KVbT, Ks, Ktot);
    dim3 gc(NT, NHEAD, 2);
    phasec_kernel<<<gc, 256, 0, stream>>>(qp, kp, vhb, KVbT, Ks, Ktot, attn);
    dim3 g(DMODEL / 64, NSEQ / 64);
    fgemm_kernel<<<g, 256, 0, stream>>>(attn, Wfc, out, bfc, q);
}

// Round 9
// 100.148 us; speedup vs baseline: 1.1535x; 1.1535x over previous
//
#include <hip/hip_runtime.h>
#include <math.h>

#define DMODEL 512
#define NSEQ 2048
#define NHEAD 8
#define DK 64
#define DV 64
#define MFEAT 266
#define MPAD 288        // padded feature dim for bf16 MFMA (zero tail), mult of 32
#define NT 32           // number of chunks (chunk = 64)
#define LN_EPS 1e-6f
#define KERNEL_EPS 1e-4f
#define NORM_STAB 1e-6f
#define SCALE 0.21022410381342863f  // 512^-0.25

typedef __attribute__((ext_vector_type(8))) short short8;
typedef __attribute__((ext_vector_type(4))) short sv4;
typedef __attribute__((ext_vector_type(4))) float f32x4;

__device__ inline short f2bf(float f) {
    unsigned u = __builtin_bit_cast(unsigned, f);
    unsigned r = (u + 0x7fff + ((u >> 16) & 1)) >> 16;
    return (short)r;
}
__device__ inline float bf2f(short s) {
    unsigned u = ((unsigned)(unsigned short)s) << 16;
    return __builtin_bit_cast(float, u);
}

// ---------------- LN stats: per-row mu, rstd (one wave per row) ----------------
__global__ __launch_bounds__(256) void ln_stats_kernel(const float* __restrict__ q,
                                                       float* __restrict__ mu,
                                                       float* __restrict__ rstd) {
    int row = blockIdx.x * 4 + (threadIdx.x >> 6);
    int lane = threadIdx.x & 63;
    const float* x = q + (size_t)row * DMODEL + lane * 8;
    f32x4 a = *(const f32x4*)x;
    f32x4 b = *(const f32x4*)(x + 4);
    float s = a[0] + a[1] + a[2] + a[3] + b[0] + b[1] + b[2] + b[3];
    float ss = a[0]*a[0] + a[1]*a[1] + a[2]*a[2] + a[3]*a[3]
             + b[0]*b[0] + b[1]*b[1] + b[2]*b[2] + b[3]*b[3];
    for (int o = 32; o > 0; o >>= 1) {
        s += __shfl_down(s, o);
        ss += __shfl_down(ss, o);
    }
    if (lane == 0) {
        float m = s / (float)DMODEL;
        float var = ss / (float)DMODEL - m * m;
        mu[row] = m;
        rstd[row] = rsqrtf(var + LN_EPS);
    }
}

// ---------------- fused QKV bf16 MFMA GEMM; z=0 applies LN; z=1 emits h_k; bf16 outputs ----------------
__global__ __launch_bounds__(256) void qkv_kernel(const float* __restrict__ qx,
                                                  const float* __restrict__ kx,
                                                  const float* __restrict__ vx,
                                                  const float* __restrict__ Wq,
                                                  const float* __restrict__ Wk,
                                                  const float* __restrict__ Wv,
                                                  const float* __restrict__ mu,
                                                  const float* __restrict__ rstd,
                                                  const float* __restrict__ gamma,
                                                  const float* __restrict__ beta,
                                                  short* __restrict__ qh,
                                                  short* __restrict__ kh,
                                                  short* __restrict__ vh,
                                                  float* __restrict__ hk,
                                                  float* __restrict__ partial) {
    int z = blockIdx.z;
    const float* A = (z == 0) ? qx : (z == 1) ? kx : vx;
    const float* B = (z == 0) ? Wq : (z == 1) ? Wk : Wv;
    short* C = (z == 0) ? qh : (z == 1) ? kh : vh;
    float scale = (z == 2) ? 1.f : SCALE;

    __shared__ short As[64][40];
    __shared__ short Bs[64][40];
    int bm = blockIdx.y * 64, bn = blockIdx.x * 64;
    int tid = threadIdx.x;
    int wid = tid >> 6, lane = tid & 63;
    f32x4 acc[4] = {f32x4{0,0,0,0}, f32x4{0,0,0,0}, f32x4{0,0,0,0}, f32x4{0,0,0,0}};
    int ar = tid >> 2, akq = tid & 3;
    int bkk = tid >> 3, bng = tid & 7;
    float lnm = 0.f, lnr = 0.f;
    if (z == 0) { lnm = mu[bm + ar]; lnr = rstd[bm + ar]; }
    for (int k0 = 0; k0 < DMODEL; k0 += 32) {
        {
            const float* src = A + (size_t)(bm + ar) * DMODEL + k0 + akq * 8;
            f32x4 v0 = *(const f32x4*)src;
            f32x4 v1 = *(const f32x4*)(src + 4);
            short8 sv;
            if (z == 0) {
                f32x4 g0 = *(const f32x4*)&gamma[k0 + akq * 8];
                f32x4 g1 = *(const f32x4*)&gamma[k0 + akq * 8 + 4];
                f32x4 bb0 = *(const f32x4*)&beta[k0 + akq * 8];
                f32x4 bb1 = *(const f32x4*)&beta[k0 + akq * 8 + 4];
                for (int j = 0; j < 4; ++j) {
                    sv[j] = f2bf((v0[j] - lnm) * lnr * g0[j] + bb0[j]);
                    sv[4 + j] = f2bf((v1[j] - lnm) * lnr * g1[j] + bb1[j]);
                }
            } else {
                for (int j = 0; j < 4; ++j) { sv[j] = f2bf(v0[j]); sv[4 + j] = f2bf(v1[j]); }
            }
            *(short8*)&As[ar][akq * 8] = sv;
        }
        {
            const float* src = B + (size_t)(k0 + bkk) * DMODEL + bn + bng * 8;
            f32x4 v0 = *(const f32x4*)src;
            f32x4 v1 = *(const f32x4*)(src + 4);
            for (int j = 0; j < 4; ++j) {
                Bs[bng * 8 + j][bkk] = f2bf(v0[j] * scale);
                Bs[bng * 8 + 4 + j][bkk] = f2bf(v1[j] * scale);
            }
        }
        __syncthreads();
        int row = wid * 16 + (lane & 15);
        int koff = (lane >> 4) * 8;
        short8 a = *(const short8*)&As[row][koff];
        for (int nf = 0; nf < 4; ++nf) {
            int col = nf * 16 + (lane & 15);
            short8 b = *(const short8*)&Bs[col][koff];
            acc[nf] = __builtin_amdgcn_mfma_f32_16x16x32_bf16(a, b, acc[nf], 0, 0, 0);
        }
        __syncthreads();
    }
    for (int nf = 0; nf < 4; ++nf) {
        int col = bn + nf * 16 + (lane & 15);
        for (int j = 0; j < 4; ++j) {
            int row = bm + wid * 16 + (lane >> 4) * 4 + j;
            C[(size_t)row * DMODEL + col] = f2bf(acc[nf][j]);
        }
    }
    if (z == 1) {
        __shared__ float bmax[4];
        float hvmax = -1e30f;
        for (int j = 0; j < 4; ++j) {
            float ss = 0.f;
            for (int nf = 0; nf < 4; ++nf) ss += acc[nf][j] * acc[nf][j];
            for (int o = 1; o < 16; o <<= 1) ss += __shfl_xor(ss, o);
            float hv = -0.5f * ss;
            int row = bm + wid * 16 + (lane >> 4) * 4 + j;
            if ((lane & 15) == 0) hk[(size_t)blockIdx.x * NSEQ + row] = hv;
            hvmax = fmaxf(hvmax, hv);
        }
        for (int o = 32; o > 0; o >>= 1) hvmax = fmaxf(hvmax, __shfl_down(hvmax, o));
        if (lane == 0) bmax[wid] = hvmax;
        __syncthreads();
        if (tid == 0)
            partial[blockIdx.y * 8 + blockIdx.x] =
                fmaxf(fmaxf(bmax[0], bmax[1]), fmaxf(bmax[2], bmax[3]));
    }
}

// ---------------- MFMA random feature maps -> bf16 [h][n][MPAD]; grid (nt, h, isQ) ----------------
__global__ __launch_bounds__(256) void feat_kernel(const short* __restrict__ qh,
                                                   const short* __restrict__ kh,
                                                   const float* __restrict__ rf,
                                                   const float* __restrict__ hkv,
                                                   const float* __restrict__ partial,
                                                   short* __restrict__ qp,
                                                   short* __restrict__ kp) {
    int nt = blockIdx.x, h = blockIdx.y, isQ = blockIdx.z;
    int n0 = nt * 64;
    int tid = threadIdx.x, w = tid >> 6, l = tid & 63;
    __shared__ short U[288 * 72];   // union: rfb[288][72] then kp_lds[64][296]
    __shared__ short Xs[64][72];
    __shared__ float red[4];

    // inline kstab reduce (partial[256] written by qkv z=1)
    float pm = partial[tid];
    for (int o = 32; o > 0; o >>= 1) pm = fmaxf(pm, __shfl_down(pm, o));
    if (l == 0) red[w] = pm;

    // stage rf -> bf16 rfb[m][d] (zero for m>=MFEAT)
    short (*rfb)[72] = (short(*)[72])U;
    for (int lp = 0; lp < 5; ++lp) {
        int c = tid + lp * 256;
        if (c < 288 * 4) {
            int m = c >> 2, dq = (c & 3) * 16;
            short8 s0, s1;
            if (m < MFEAT) {
                f32x4 v0 = *(const f32x4*)&rf[(size_t)m * DK + dq];
                f32x4 v1 = *(const f32x4*)&rf[(size_t)m * DK + dq + 4];
                f32x4 v2 = *(const f32x4*)&rf[(size_t)m * DK + dq + 8];
                f32x4 v3 = *(const f32x4*)&rf[(size_t)m * DK + dq + 12];
                for (int j = 0; j < 4; ++j) {
                    s0[j] = f2bf(v0[j]); s0[4 + j] = f2bf(v1[j]);
                    s1[j] = f2bf(v2[j]); s1[4 + j] = f2bf(v3[j]);
                }
            } else {
                for (int j = 0; j < 8; ++j) { s0[j] = 0; s1[j] = 0; }
            }
            *(short8*)&rfb[m][dq] = s0;
            *(short8*)&rfb[m][dq + 8] = s1;
        }
    }
    // stage X chunk (bf16) -> Xs[n][d]
    const short* xh = isQ ? qh : kh;
    {
        int n = tid >> 2, dq = (tid & 3) * 16;
        const short* src = xh + (size_t)(n0 + n) * DMODEL + h * DK + dq;
        *(short8*)&Xs[n][dq] = *(const short8*)src;
        *(short8*)&Xs[n][dq + 8] = *(const short8*)(src + 8);
    }
    __syncthreads();
    float ks = fmaxf(fmaxf(red[0], red[1]), fmaxf(red[2], red[3]));

    // proj MFMA: C[m][n] = sum_d rfb[m][d] * Xs[n][d]; wave w owns n-tile w
    int fr = l & 15, fq = (l >> 4) * 8;
    short8 xb0 = *(const short8*)&Xs[w * 16 + fr][fq];
    short8 xb1 = *(const short8*)&Xs[w * 16 + fr][32 + fq];
    f32x4 acc[18];
#pragma unroll
    for (int tr = 0; tr < 18; ++tr) acc[tr] = f32x4{0, 0, 0, 0};
#pragma unroll
    for (int tr = 0; tr < 18; ++tr) {
        short8 a0 = *(const short8*)&rfb[tr * 16 + fr][fq];
        short8 a1 = *(const short8*)&rfb[tr * 16 + fr][32 + fq];
        acc[tr] = __builtin_amdgcn_mfma_f32_16x16x32_bf16(a0, xb0, acc[tr], 0, 0, 0);
        acc[tr] = __builtin_amdgcn_mfma_f32_16x16x32_bf16(a1, xb1, acc[tr], 0, 0, 0);
    }
    __syncthreads();  // all waves done reading rfb; U becomes kp_lds

    short (*kpl)[296] = (short(*)[296])U;
    int n_loc = w * 16 + fr;
    int n = n0 + n_loc;
    const float cnorm = 0.06131393394849658f;  // 266^-0.5
    float hval = isQ ? 0.f : (hkv[(size_t)h * NSEQ + n] - ks);
#pragma unroll
    for (int tr = 0; tr < 18; ++tr) {
        sv4 o;
        for (int j = 0; j < 4; ++j) {
            int m = tr * 16 + (l >> 4) * 4 + j;
            float val = (m < MFEAT) ? cnorm * (expf(acc[tr][j] + hval) + KERNEL_EPS) : 0.f;
            o[j] = f2bf(val);
        }
        *(sv4*)&kpl[n_loc][tr * 16 + (l >> 4) * 4] = o;
    }
    __syncthreads();
    // coalesced copy kp_lds rows -> HBM
    short* outp = isQ ? qp : kp;
    for (int lp = 0; lp < 9; ++lp) {
        int c = tid + lp * 256;      // 64 rows * 36 chunks
        int nn = c / 36, c8 = c % 36;
        short8 v = *(const short8*)&kpl[nn][c8 * 8];
        *(short8*)&outp[((size_t)h * NSEQ + n0 + nn) * MPAD + c8 * 8] = v;
    }
}

// ---------------- phase A (MFMA): per-chunk sums -> bf16 KVc[(h,t,dv)][m], fp32 Ks[(h,t)][m] ----------------
// grid (t, h). kp^T staged in LDS with XOR group-swizzle to avoid transpose bank conflicts.
__global__ __launch_bounds__(256) void chunksum_kernel(const short* __restrict__ kp,
                                                       const short* __restrict__ vh,
                                                       short* __restrict__ KVc,
                                                       float* __restrict__ Ks) {
    int t = blockIdx.x, h = blockIdx.y;
    __shared__ short kpT[288 * 72];   // [m][i-swizzled], stride 72 shorts (144B); 41.5KB
    __shared__ short Vt[64][72];      // [dv][i]
    int tid = threadIdx.x;
    int w = tid >> 6, l = tid & 63;
    int fr = l & 15, fq8 = (l >> 4) * 8;
    const short* kpb = kp + ((size_t)h * NSEQ + (size_t)t * 64) * MPAD;

    // stage kp^T: read rows coalesced, scatter to swizzled columns
    for (int lp = 0; lp < 9; ++lp) {
        int c = tid + lp * 256;       // 2304 = 64 i * 36 m-chunks
        int i = c / 36, c8 = c % 36;
        short8 v = *(const short8*)&kpb[(size_t)i * MPAD + c8 * 8];
        int i8 = i >> 3, i7 = i & 7;
        for (int jj = 0; jj < 8; ++jj) {
            int m = c8 * 8 + jj;
            int ig = i8 ^ ((m >> 3) & 7);
            kpT[m * 72 + ig * 8 + i7] = v[jj];
        }
    }
    // stage V^T: lanes walk i (conflict-free LDS writes)
    for (int lp = 0; lp < 2; ++lp) {
        int c = tid + lp * 256;       // 512 = 64 i * 8 d-chunks
        int i = c & 63, d8 = (c >> 6) * 8;
        short8 v = *(const short8*)&vh[(size_t)(t * 64 + i) * DMODEL + h * DV + d8];
        for (int jj = 0; jj < 8; ++jj) Vt[d8 + jj][i] = v[jj];
    }
    __syncthreads();

    // D[m][dv] = sum_i kp^T[m][i] * V[i][dv]; wave w owns m-tiles {w, w+4, ...}
    f32x4 acc[5][4];
#pragma unroll
    for (int tt = 0; tt < 5; ++tt)
        for (int nf = 0; nf < 4; ++nf) acc[tt][nf] = f32x4{0, 0, 0, 0};
#pragma unroll
    for (int tt = 0; tt < 5; ++tt) {
        int tr = w + tt * 4;
        if (tr < 18) {
            int row = tr * 16 + fr;
            int swz = (row >> 3) & 7;
            short8 a0 = *(const short8*)&kpT[row * 72 + (((fq8 >> 3)) ^ swz) * 8];
            short8 a1 = *(const short8*)&kpT[row * 72 + ((4 + (fq8 >> 3)) ^ swz) * 8];
            for (int nf = 0; nf < 4; ++nf) {
                short8 b0 = *(const short8*)&Vt[nf * 16 + fr][fq8];
                short8 b1 = *(const short8*)&Vt[nf * 16 + fr][32 + fq8];
                acc[tt][nf] = __builtin_amdgcn_mfma_f32_16x16x32_bf16(a0, b0, acc[tt][nf], 0, 0, 0);
                acc[tt][nf] = __builtin_amdgcn_mfma_f32_16x16x32_bf16(a1, b1, acc[tt][nf], 0, 0, 0);
            }
        }
    }
    // Ks[m] = sum_i kp^T[m][i]
    for (int m = tid; m < MPAD; m += 256) {
        int swz = (m >> 3) & 7;
        float s = 0.f;
        for (int i8 = 0; i8 < 8; ++i8) {
            int ig = i8 ^ swz;
            for (int j = 0; j < 8; ++j) s += bf2f(kpT[m * 72 + ig * 8 + j]);
        }
        Ks[((size_t)h * NT + t) * MPAD + m] = s;
    }
    __syncthreads();  // kpT reads done; overlay kvT
    short* kvT = kpT; // [64 dv][296 m] = 37.9KB <= 41.5KB
#pragma unroll
    for (int tt = 0; tt < 5; ++tt) {
        int tr = w + tt * 4;
        if (tr < 18) {
            for (int nf = 0; nf < 4; ++nf) {
                int dv = nf * 16 + fr;
                for (int j = 0; j < 4; ++j) {
                    int m = tr * 16 + (l >> 4) * 4 + j;
                    kvT[dv * 296 + m] = f2bf(acc[tt][nf][j]);
                }
            }
        }
    }
    __syncthreads();
    // coalesced KVc store
    for (int lp = 0; lp < 9; ++lp) {
        int c = tid + lp * 256;       // 2304 = 64 dv * 36
        int dv = c / 36, c8 = c % 36;
        short8 v = *(const short8*)&kvT[dv * 296 + c8 * 8];
        *(short8*)&KVc[(((size_t)h * NT + t) * DV + dv) * MPAD + c8 * 8] = v;
    }
}

// ---------------- fused exclusive chunk-scans (bf16 KVc -> bf16 S^T, Ks -> prefix + Ktot) ----------------
__global__ void scan_kernel(const short* __restrict__ KVc, short* __restrict__ KVbT,
                            float* __restrict__ Ks, float* __restrict__ Ktot) {
    int idx = blockIdx.x * 256 + threadIdx.x;
    const int NKV = NHEAD * DV * MPAD;       // 147456
    if (idx < NKV) {
        int h = idx / (DV * MPAD);
        int rem = idx % (DV * MPAD);
        size_t base = (size_t)h * NT * DV * MPAD + rem;
        float run = 0.f;
        for (int t = 0; t < NT; ++t) {
            size_t o = base + (size_t)t * DV * MPAD;
            KVbT[o] = f2bf(run);
            run += bf2f(KVc[o]);
        }
    } else {
        int j = idx - NKV;
        if (j < NHEAD * MPAD) {
            int h = j / MPAD, m = j % MPAD;
            size_t base = (size_t)h * NT * MPAD + m;
            float run = 0.f;
            for (int t = 0; t < NT; ++t) {
                size_t o = base + (size_t)t * MPAD;
                float v = Ks[o];
                Ks[o] = run;
                run += v;
            }
            Ktot[(size_t)h * MPAD + m] = run;
        }
    }
}

// ---------------- phase C: MFMA intra+inter+denominators; grid (t, h) ----------------
__global__ __launch_bounds__(256) void phasec_kernel(const short* __restrict__ qp,
                                                     const short* __restrict__ kp,
                                                     const short* __restrict__ vh,
                                                     const short* __restrict__ KVbT,
                                                     const float* __restrict__ Ks,
                                                     const float* __restrict__ Ktot,
                                                     float* __restrict__ attn) {
    int t = blockIdx.x, h = blockIdx.y;
    __shared__ short Buf[64][296];   // Kp (QK^T phase) then St (inter phase)
    __shared__ short Vt[64][72];     // [dv][i]
    __shared__ short Am[64][72];     // masked A, bf16
    __shared__ float Ksp[MPAD], Ktp[MPAD];
    __shared__ float fscale_s[64];
    int tid = threadIdx.x;
    int w = tid >> 6, l = tid & 63;
    int fr = l & 15, fq = (l >> 4) * 8;
    const short* qpb = qp + ((size_t)h * NSEQ + (size_t)t * 64) * MPAD;
    const short* kpb = kp + ((size_t)h * NSEQ + (size_t)t * 64) * MPAD;
    const short* stb = KVbT + ((size_t)h * NT + t) * DV * MPAD;

    short8 qf[9];
#pragma unroll
    for (int ks = 0; ks < 9; ++ks)
        qf[ks] = *(const short8*)&qpb[(size_t)(w * 16 + fr) * MPAD + ks * 32 + fq];

    int srow = tid >> 2, sc4 = tid & 3;
#pragma unroll
    for (int lp = 0; lp < 9; ++lp) {
        int c = sc4 + lp * 4;
        *(short8*)&Buf[srow][c * 8] = *(const short8*)&kpb[(size_t)srow * MPAD + c * 8];
    }
    {
        int dv = tid >> 2, iq = (tid & 3) * 16;
        short8 v0, v1;
        for (int it = 0; it < 8; ++it)
            v0[it] = vh[(size_t)(t * 64 + iq + it) * DMODEL + h * DV + dv];
        for (int it = 0; it < 8; ++it)
            v1[it] = vh[(size_t)(t * 64 + iq + 8 + it) * DMODEL + h * DV + dv];
        *(short8*)&Vt[dv][iq] = v0;
        *(short8*)&Vt[dv][iq + 8] = v1;
    }
    for (int idx = tid; idx < MPAD; idx += 256) {
        Ksp[idx] = Ks[((size_t)h * NT + t) * MPAD + idx];
        Ktp[idx] = Ktot[(size_t)h * MPAD + idx];
    }
    __syncthreads();

    f32x4 accA[4] = {f32x4{0,0,0,0}, f32x4{0,0,0,0}, f32x4{0,0,0,0}, f32x4{0,0,0,0}};
    f32x4 accO[4] = {f32x4{0,0,0,0}, f32x4{0,0,0,0}, f32x4{0,0,0,0}, f32x4{0,0,0,0}};
#pragma unroll 3
    for (int ks = 0; ks < 9; ++ks) {
        int ko = ks * 32 + fq;
        for (int nf = 0; nf < 4; ++nf) {
            short8 bk = *(const short8*)&Buf[nf * 16 + fr][ko];
            accA[nf] = __builtin_amdgcn_mfma_f32_16x16x32_bf16(qf[ks], bk, accA[nf], 0, 0, 0);
        }
    }
    __syncthreads();
#pragma unroll
    for (int lp = 0; lp < 9; ++lp) {
        int c = sc4 + lp * 4;
        *(short8*)&Buf[srow][c * 8] = *(const short8*)&stb[(size_t)srow * MPAD + c * 8];
    }
    for (int nf = 0; nf < 4; ++nf) {
        int col = nf * 16 + fr;
        for (int j = 0; j < 4; ++j) {
            int row = w * 16 + (l >> 4) * 4 + j;
            Am[row][col] = (col <= row) ? f2bf(accA[nf][j]) : (short)0;
        }
    }
    __syncthreads();
#pragma unroll 3
    for (int ks = 0; ks < 9; ++ks) {
        int ko = ks * 32 + fq;
        for (int nf = 0; nf < 4; ++nf) {
            short8 bs = *(const short8*)&Buf[nf * 16 + fr][ko];
            accO[nf] = __builtin_amdgcn_mfma_f32_16x16x32_bf16(qf[ks], bs, accO[nf], 0, 0, 0);
        }
    }
#pragma unroll
    for (int ks = 0; ks < 2; ++ks) {
        int ko = ks * 32 + fq;
        short8 a = *(const short8*)&Am[w * 16 + fr][ko];
        for (int nf = 0; nf < 4; ++nf) {
            short8 b = *(const short8*)&Vt[nf * 16 + fr][ko];
            accO[nf] = __builtin_amdgcn_mfma_f32_16x16x32_bf16(a, b, accO[nf], 0, 0, 0);
        }
    }
    int di = tid >> 2, dp = tid & 3;
    float dc = 0.f, df = 0.f;
    {
        const short* amrow = &Am[di][dp * 16];
        short8 s0 = *(const short8*)amrow;
        short8 s1 = *(const short8*)(amrow + 8);
        for (int j2 = 0; j2 < 8; ++j2) dc += bf2f(s0[j2]) + bf2f(s1[j2]);
    }
#pragma unroll
    for (int c8 = 0; c8 < 9; ++c8) {
        int m = dp * 72 + c8 * 8;
        short8 qv = *(const short8*)&qpb[(size_t)di * MPAD + m];
        for (int j2 = 0; j2 < 8; ++j2) {
            float qq = bf2f(qv[j2]);
            dc += qq * Ksp[m + j2];
            df += qq * Ktp[m + j2];
        }
    }
    dc += __shfl_xor(dc, 1); dc += __shfl_xor(dc, 2);
    df += __shfl_xor(df, 1); df += __shfl_xor(df, 2);
    if (dp == 0) {
        float dst = df;
        if (fabsf(dst) <= NORM_STAB) dst += 2.f * NORM_STAB;
        fscale_s[di] = (1.f / dc) / dst;
    }
    __syncthreads();
    for (int nf = 0; nf < 4; ++nf) {
        int col = nf * 16 + fr;
        for (int j = 0; j < 4; ++j) {
            int row = w * 16 + (l >> 4) * 4 + j;
            attn[((size_t)t * 64 + row) * DMODEL + h * DV + col] = accO[nf][j] * fscale_s[row];
        }
    }
}

// ---------------- final GEMM with bias + residual ----------------
__global__ __launch_bounds__(256) void fgemm_kernel(const float* __restrict__ A,
                                                    const float* __restrict__ B,
                                                    float* __restrict__ C,
                                                    const float* __restrict__ bias,
                                                    const float* __restrict__ residual) {
    __shared__ short As[64][40];
    __shared__ short Bs[64][40];
    int bm = blockIdx.y * 64, bn = blockIdx.x * 64;
    int tid = threadIdx.x;
    int wid = tid >> 6, lane = tid & 63;
    f32x4 acc[4] = {f32x4{0,0,0,0}, f32x4{0,0,0,0}, f32x4{0,0,0,0}, f32x4{0,0,0,0}};
    int ar = tid >> 2, akq = tid & 3;
    int bkk = tid >> 3, bng = tid & 7;
    for (int k0 = 0; k0 < DMODEL; k0 += 32) {
        {
            const float* src = A + (size_t)(bm + ar) * DMODEL + k0 + akq * 8;
            f32x4 v0 = *(const f32x4*)src;
            f32x4 v1 = *(const f32x4*)(src + 4);
            short8 sv;
            for (int j = 0; j < 4; ++j) { sv[j] = f2bf(v0[j]); sv[4 + j] = f2bf(v1[j]); }
            *(short8*)&As[ar][akq * 8] = sv;
        }
        {
            const float* src = B + (size_t)(k0 + bkk) * DMODEL + bn + bng * 8;
            f32x4 v0 = *(const f32x4*)src;
            f32x4 v1 = *(const f32x4*)(src + 4);
            for (int j = 0; j < 4; ++j) {
                Bs[bng * 8 + j][bkk] = f2bf(v0[j]);
                Bs[bng * 8 + 4 + j][bkk] = f2bf(v1[j]);
            }
        }
        __syncthreads();
        int row = wid * 16 + (lane & 15);
        int koff = (lane >> 4) * 8;
        short8 a = *(const short8*)&As[row][koff];
        for (int nf = 0; nf < 4; ++nf) {
            int col = nf * 16 + (lane & 15);
            short8 b = *(const short8*)&Bs[col][koff];
            acc[nf] = __builtin_amdgcn_mfma_f32_16x16x32_bf16(a, b, acc[nf], 0, 0, 0);
        }
        __syncthreads();
    }
    for (int nf = 0; nf < 4; ++nf) {
        int col = bn + nf * 16 + (lane & 15);
        for (int j = 0; j < 4; ++j) {
            int row = bm + wid * 16 + (lane >> 4) * 4 + j;
            C[(size_t)row * DMODEL + col] =
                acc[nf][j] + bias[col] + residual[(size_t)row * DMODEL + col];
        }
    }
}

extern "C" void kernel_launch(void* const* d_in, const int* in_sizes, int n_in,
                              void* d_out, int out_size, void* d_ws, size_t ws_size,
                              hipStream_t stream) {
    const float* q = (const float*)d_in[0];
    const float* k = (const float*)d_in[1];
    const float* v = (const float*)d_in[2];
    const float* Wq = (const float*)d_in[3];
    const float* Wk = (const float*)d_in[4];
    const float* Wv = (const float*)d_in[5];
    const float* Wfc = (const float*)d_in[6];
    const float* bfc = (const float*)d_in[7];
    const float* gamma = (const float*)d_in[8];
    const float* beta = (const float*)d_in[9];
    const float* rf = (const float*)d_in[10];
    float* out = (float*)d_out;

    float* ws = (float*)d_ws;
    float* attn = ws;                                      // fp32 2048*512
    short* qh = (short*)(attn + (size_t)NSEQ * DMODEL);    // bf16 2048*512
    short* kh = qh + (size_t)NSEQ * DMODEL;                // bf16 2048*512
    short* vhb = kh + (size_t)NSEQ * DMODEL;               // bf16 2048*512
    short* qp = vhb + (size_t)NSEQ * DMODEL;               // bf16 8*2048*288
    short* kp = qp + (size_t)NHEAD * NSEQ * MPAD;          // bf16 8*2048*288
    short* KVc = kp + (size_t)NHEAD * NSEQ * MPAD;         // bf16 8*32*64*288
    short* KVbT = KVc + (size_t)NHEAD * NT * DV * MPAD;    // bf16 8*32*64*288
    float* Ks = (float*)(KVbT + (size_t)NHEAD * NT * DV * MPAD);   // fp32 8*32*288
    float* Ktot = Ks + (size_t)NHEAD * NT * MPAD;          // 8*288
    float* hk = Ktot + (size_t)NHEAD * MPAD;               // 8*2048
    float* partial = hk + (size_t)NHEAD * NSEQ;            // 256
    float* mu = partial + 256;                             // 2048
    float* rstd = mu + NSEQ;                               // 2048

    ln_stats_kernel<<<NSEQ / 4, 256, 0, stream>>>(q, mu, rstd);
    dim3 gq(DMODEL / 64, NSEQ / 64, 3);
    qkv_kernel<<<gq, 256, 0, stream>>>(q, k, v, Wq, Wk, Wv, mu, rstd, gamma, beta,
                                       qh, kh, vhb, hk, partial);
    dim3 gf(NT, NHEAD, 2);
    feat_kernel<<<gf, 256, 0, stream>>>(qh, kh, rf, hk, partial, qp, kp);
    dim3 ga(NT, NHEAD);
    chunksum_kernel<<<ga, 256, 0, stream>>>(kp, vhb, KVc, Ks);
    int scan_threads = NHEAD * DV * MPAD + NHEAD * MPAD;
    scan_kernel<<<(scan_threads + 255) / 256, 256, 0, stream>>>(KVc, KVbT, Ks, Ktot);
    dim3 gc(NT, NHEAD);
    phasec_kernel<<<gc, 256, 0, stream>>>(qp, kp, vhb, KVbT, Ks, Ktot, attn);
    dim3 g(DMODEL / 64, NSEQ / 64);
    fgemm_kernel<<<g, 256, 0, stream>>>(attn, Wfc, out, bfc, q);
}

// Round 10
// 96.338 us; speedup vs baseline: 1.1991x; 1.0395x over previous
//
#include <hip/hip_runtime.h>
#include <math.h>

#define DMODEL 512
#define NSEQ 2048
#define NHEAD 8
#define DK 64
#define DV 64
#define MFEAT 266
#define MPAD 288        // padded feature dim for bf16 MFMA (zero tail), mult of 32
#define NT 32           // number of chunks (chunk = 64)
#define LN_EPS 1e-6f
#define KERNEL_EPS 1e-4f
#define NORM_STAB 1e-6f
#define SCALE 0.21022410381342863f  // 512^-0.25

typedef __attribute__((ext_vector_type(8))) short short8;
typedef __attribute__((ext_vector_type(4))) short sv4;
typedef __attribute__((ext_vector_type(4))) float f32x4;

__device__ inline short f2bf(float f) {
    unsigned u = __builtin_bit_cast(unsigned, f);
    unsigned r = (u + 0x7fff + ((u >> 16) & 1)) >> 16;
    return (short)r;
}
__device__ inline float bf2f(short s) {
    unsigned u = ((unsigned)(unsigned short)s) << 16;
    return __builtin_bit_cast(float, u);
}

// ---------------- fused QKV bf16 MFMA GEMM; z=0 computes+applies LN inline; z=1 emits h_k ----------------
__global__ __launch_bounds__(256) void qkv_kernel(const float* __restrict__ qx,
                                                  const float* __restrict__ kx,
                                                  const float* __restrict__ vx,
                                                  const float* __restrict__ Wq,
                                                  const float* __restrict__ Wk,
                                                  const float* __restrict__ Wv,
                                                  const float* __restrict__ gamma,
                                                  const float* __restrict__ beta,
                                                  short* __restrict__ qh,
                                                  short* __restrict__ kh,
                                                  short* __restrict__ vh,
                                                  float* __restrict__ hk,
                                                  float* __restrict__ partial) {
    int z = blockIdx.z;
    const float* A = (z == 0) ? qx : (z == 1) ? kx : vx;
    const float* B = (z == 0) ? Wq : (z == 1) ? Wk : Wv;
    short* C = (z == 0) ? qh : (z == 1) ? kh : vh;
    float scale = (z == 2) ? 1.f : SCALE;

    __shared__ short As[64][40];
    __shared__ short Bs[64][40];
    int bm = blockIdx.y * 64, bn = blockIdx.x * 64;
    int tid = threadIdx.x;
    int wid = tid >> 6, lane = tid & 63;
    f32x4 acc[4] = {f32x4{0,0,0,0}, f32x4{0,0,0,0}, f32x4{0,0,0,0}, f32x4{0,0,0,0}};
    int ar = tid >> 2, akq = tid & 3;
    int bkk = tid >> 3, bng = tid & 7;
    float lnm = 0.f, lnr = 0.f;
    if (z == 0) {
        // per-quad LN stats for row bm+ar (4 threads per row, contiguous lanes)
        const float* xr = qx + (size_t)(bm + ar) * DMODEL + akq * 128;
        float s = 0.f, ss = 0.f;
#pragma unroll 4
        for (int i = 0; i < 128; i += 4) {
            f32x4 vv = *(const f32x4*)(xr + i);
            s += vv[0] + vv[1] + vv[2] + vv[3];
            ss += vv[0]*vv[0] + vv[1]*vv[1] + vv[2]*vv[2] + vv[3]*vv[3];
        }
        s += __shfl_xor(s, 1); s += __shfl_xor(s, 2);
        ss += __shfl_xor(ss, 1); ss += __shfl_xor(ss, 2);
        float m = s / (float)DMODEL;
        float var = ss / (float)DMODEL - m * m;
        lnm = m;
        lnr = rsqrtf(var + LN_EPS);
    }
    for (int k0 = 0; k0 < DMODEL; k0 += 32) {
        {
            const float* src = A + (size_t)(bm + ar) * DMODEL + k0 + akq * 8;
            f32x4 v0 = *(const f32x4*)src;
            f32x4 v1 = *(const f32x4*)(src + 4);
            short8 sv;
            if (z == 0) {
                f32x4 g0 = *(const f32x4*)&gamma[k0 + akq * 8];
                f32x4 g1 = *(const f32x4*)&gamma[k0 + akq * 8 + 4];
                f32x4 bb0 = *(const f32x4*)&beta[k0 + akq * 8];
                f32x4 bb1 = *(const f32x4*)&beta[k0 + akq * 8 + 4];
                for (int j = 0; j < 4; ++j) {
                    sv[j] = f2bf((v0[j] - lnm) * lnr * g0[j] + bb0[j]);
                    sv[4 + j] = f2bf((v1[j] - lnm) * lnr * g1[j] + bb1[j]);
                }
            } else {
                for (int j = 0; j < 4; ++j) { sv[j] = f2bf(v0[j]); sv[4 + j] = f2bf(v1[j]); }
            }
            *(short8*)&As[ar][akq * 8] = sv;
        }
        {
            const float* src = B + (size_t)(k0 + bkk) * DMODEL + bn + bng * 8;
            f32x4 v0 = *(const f32x4*)src;
            f32x4 v1 = *(const f32x4*)(src + 4);
            for (int j = 0; j < 4; ++j) {
                Bs[bng * 8 + j][bkk] = f2bf(v0[j] * scale);
                Bs[bng * 8 + 4 + j][bkk] = f2bf(v1[j] * scale);
            }
        }
        __syncthreads();
        int row = wid * 16 + (lane & 15);
        int koff = (lane >> 4) * 8;
        short8 a = *(const short8*)&As[row][koff];
        for (int nf = 0; nf < 4; ++nf) {
            int col = nf * 16 + (lane & 15);
            short8 b = *(const short8*)&Bs[col][koff];
            acc[nf] = __builtin_amdgcn_mfma_f32_16x16x32_bf16(a, b, acc[nf], 0, 0, 0);
        }
        __syncthreads();
    }
    for (int nf = 0; nf < 4; ++nf) {
        int col = bn + nf * 16 + (lane & 15);
        for (int j = 0; j < 4; ++j) {
            int row = bm + wid * 16 + (lane >> 4) * 4 + j;
            C[(size_t)row * DMODEL + col] = f2bf(acc[nf][j]);
        }
    }
    if (z == 1) {
        __shared__ float bmax[4];
        float hvmax = -1e30f;
        for (int j = 0; j < 4; ++j) {
            float ss = 0.f;
            for (int nf = 0; nf < 4; ++nf) ss += acc[nf][j] * acc[nf][j];
            for (int o = 1; o < 16; o <<= 1) ss += __shfl_xor(ss, o);
            float hv = -0.5f * ss;
            int row = bm + wid * 16 + (lane >> 4) * 4 + j;
            if ((lane & 15) == 0) hk[(size_t)blockIdx.x * NSEQ + row] = hv;
            hvmax = fmaxf(hvmax, hv);
        }
        for (int o = 32; o > 0; o >>= 1) hvmax = fmaxf(hvmax, __shfl_down(hvmax, o));
        if (lane == 0) bmax[wid] = hvmax;
        __syncthreads();
        if (tid == 0)
            partial[blockIdx.y * 8 + blockIdx.x] =
                fmaxf(fmaxf(bmax[0], bmax[1]), fmaxf(bmax[2], bmax[3]));
    }
}

// ---------------- MFMA random feature maps -> bf16 [h][n][MPAD]; grid (nt, h, isQ) ----------------
__global__ __launch_bounds__(256) void feat_kernel(const short* __restrict__ qh,
                                                   const short* __restrict__ kh,
                                                   const float* __restrict__ rf,
                                                   const float* __restrict__ hkv,
                                                   const float* __restrict__ partial,
                                                   short* __restrict__ qp,
                                                   short* __restrict__ kp) {
    int nt = blockIdx.x, h = blockIdx.y, isQ = blockIdx.z;
    int n0 = nt * 64;
    int tid = threadIdx.x, w = tid >> 6, l = tid & 63;
    __shared__ short U[288 * 72];   // union: rfb[288][72] then kp_lds[64][296]
    __shared__ short Xs[64][72];
    __shared__ float red[4];

    // inline kstab reduce (partial[256] written by qkv z=1)
    float pm = partial[tid];
    for (int o = 32; o > 0; o >>= 1) pm = fmaxf(pm, __shfl_down(pm, o));
    if (l == 0) red[w] = pm;

    // stage rf -> bf16 rfb[m][d] (zero for m>=MFEAT)
    short (*rfb)[72] = (short(*)[72])U;
    for (int lp = 0; lp < 5; ++lp) {
        int c = tid + lp * 256;
        if (c < 288 * 4) {
            int m = c >> 2, dq = (c & 3) * 16;
            short8 s0, s1;
            if (m < MFEAT) {
                f32x4 v0 = *(const f32x4*)&rf[(size_t)m * DK + dq];
                f32x4 v1 = *(const f32x4*)&rf[(size_t)m * DK + dq + 4];
                f32x4 v2 = *(const f32x4*)&rf[(size_t)m * DK + dq + 8];
                f32x4 v3 = *(const f32x4*)&rf[(size_t)m * DK + dq + 12];
                for (int j = 0; j < 4; ++j) {
                    s0[j] = f2bf(v0[j]); s0[4 + j] = f2bf(v1[j]);
                    s1[j] = f2bf(v2[j]); s1[4 + j] = f2bf(v3[j]);
                }
            } else {
                for (int j = 0; j < 8; ++j) { s0[j] = 0; s1[j] = 0; }
            }
            *(short8*)&rfb[m][dq] = s0;
            *(short8*)&rfb[m][dq + 8] = s1;
        }
    }
    // stage X chunk (bf16) -> Xs[n][d]
    const short* xh = isQ ? qh : kh;
    {
        int n = tid >> 2, dq = (tid & 3) * 16;
        const short* src = xh + (size_t)(n0 + n) * DMODEL + h * DK + dq;
        *(short8*)&Xs[n][dq] = *(const short8*)src;
        *(short8*)&Xs[n][dq + 8] = *(const short8*)(src + 8);
    }
    __syncthreads();
    float ks = fmaxf(fmaxf(red[0], red[1]), fmaxf(red[2], red[3]));

    // proj MFMA: C[m][n] = sum_d rfb[m][d] * Xs[n][d]; wave w owns n-tile w
    int fr = l & 15, fq = (l >> 4) * 8;
    short8 xb0 = *(const short8*)&Xs[w * 16 + fr][fq];
    short8 xb1 = *(const short8*)&Xs[w * 16 + fr][32 + fq];
    f32x4 acc[18];
#pragma unroll
    for (int tr = 0; tr < 18; ++tr) acc[tr] = f32x4{0, 0, 0, 0};
#pragma unroll
    for (int tr = 0; tr < 18; ++tr) {
        short8 a0 = *(const short8*)&rfb[tr * 16 + fr][fq];
        short8 a1 = *(const short8*)&rfb[tr * 16 + fr][32 + fq];
        acc[tr] = __builtin_amdgcn_mfma_f32_16x16x32_bf16(a0, xb0, acc[tr], 0, 0, 0);
        acc[tr] = __builtin_amdgcn_mfma_f32_16x16x32_bf16(a1, xb1, acc[tr], 0, 0, 0);
    }
    __syncthreads();  // all waves done reading rfb; U becomes kp_lds

    short (*kpl)[296] = (short(*)[296])U;
    int n_loc = w * 16 + fr;
    int n = n0 + n_loc;
    const float cnorm = 0.06131393394849658f;  // 266^-0.5
    float hval = isQ ? 0.f : (hkv[(size_t)h * NSEQ + n] - ks);
#pragma unroll
    for (int tr = 0; tr < 18; ++tr) {
        sv4 o;
        for (int j = 0; j < 4; ++j) {
            int m = tr * 16 + (l >> 4) * 4 + j;
            float val = (m < MFEAT) ? cnorm * (expf(acc[tr][j] + hval) + KERNEL_EPS) : 0.f;
            o[j] = f2bf(val);
        }
        *(sv4*)&kpl[n_loc][tr * 16 + (l >> 4) * 4] = o;
    }
    __syncthreads();
    // coalesced copy kp_lds rows -> HBM
    short* outp = isQ ? qp : kp;
    for (int lp = 0; lp < 9; ++lp) {
        int c = tid + lp * 256;      // 64 rows * 36 chunks
        int nn = c / 36, c8 = c % 36;
        short8 v = *(const short8*)&kpl[nn][c8 * 8];
        *(short8*)&outp[((size_t)h * NSEQ + n0 + nn) * MPAD + c8 * 8] = v;
    }
}

// ---------------- phase A (MFMA): per-chunk sums -> bf16 KVc[(h,t,dv)][m], fp32 Ks[(h,t)][m] ----------------
__global__ __launch_bounds__(256) void chunksum_kernel(const short* __restrict__ kp,
                                                       const short* __restrict__ vh,
                                                       short* __restrict__ KVc,
                                                       float* __restrict__ Ks) {
    int t = blockIdx.x, h = blockIdx.y;
    __shared__ short kpT[288 * 72];   // [m][i-swizzled], stride 72 shorts (144B); 41.5KB
    __shared__ short Vt[64][72];      // [dv][i]
    int tid = threadIdx.x;
    int w = tid >> 6, l = tid & 63;
    int fr = l & 15, fq8 = (l >> 4) * 8;
    const short* kpb = kp + ((size_t)h * NSEQ + (size_t)t * 64) * MPAD;

    // stage kp^T: read rows coalesced, scatter to swizzled columns
    for (int lp = 0; lp < 9; ++lp) {
        int c = tid + lp * 256;       // 2304 = 64 i * 36 m-chunks
        int i = c / 36, c8 = c % 36;
        short8 v = *(const short8*)&kpb[(size_t)i * MPAD + c8 * 8];
        int i8 = i >> 3, i7 = i & 7;
        for (int jj = 0; jj < 8; ++jj) {
            int m = c8 * 8 + jj;
            int ig = i8 ^ ((m >> 3) & 7);
            kpT[m * 72 + ig * 8 + i7] = v[jj];
        }
    }
    // stage V^T
    for (int lp = 0; lp < 2; ++lp) {
        int c = tid + lp * 256;       // 512 = 64 i * 8 d-chunks
        int i = c & 63, d8 = (c >> 6) * 8;
        short8 v = *(const short8*)&vh[(size_t)(t * 64 + i) * DMODEL + h * DV + d8];
        for (int jj = 0; jj < 8; ++jj) Vt[d8 + jj][i] = v[jj];
    }
    __syncthreads();

    // D[m][dv] = sum_i kp^T[m][i] * V[i][dv]; wave w owns m-tiles {w, w+4, ...}
    f32x4 acc[5][4];
#pragma unroll
    for (int tt = 0; tt < 5; ++tt)
        for (int nf = 0; nf < 4; ++nf) acc[tt][nf] = f32x4{0, 0, 0, 0};
#pragma unroll
    for (int tt = 0; tt < 5; ++tt) {
        int tr = w + tt * 4;
        if (tr < 18) {
            int row = tr * 16 + fr;
            int swz = (row >> 3) & 7;
            short8 a0 = *(const short8*)&kpT[row * 72 + (((fq8 >> 3)) ^ swz) * 8];
            short8 a1 = *(const short8*)&kpT[row * 72 + ((4 + (fq8 >> 3)) ^ swz) * 8];
            for (int nf = 0; nf < 4; ++nf) {
                short8 b0 = *(const short8*)&Vt[nf * 16 + fr][fq8];
                short8 b1 = *(const short8*)&Vt[nf * 16 + fr][32 + fq8];
                acc[tt][nf] = __builtin_amdgcn_mfma_f32_16x16x32_bf16(a0, b0, acc[tt][nf], 0, 0, 0);
                acc[tt][nf] = __builtin_amdgcn_mfma_f32_16x16x32_bf16(a1, b1, acc[tt][nf], 0, 0, 0);
            }
        }
    }
    // Ks[m] = sum_i kp^T[m][i]
    for (int m = tid; m < MPAD; m += 256) {
        int swz = (m >> 3) & 7;
        float s = 0.f;
        for (int i8 = 0; i8 < 8; ++i8) {
            int ig = i8 ^ swz;
            for (int j = 0; j < 8; ++j) s += bf2f(kpT[m * 72 + ig * 8 + j]);
        }
        Ks[((size_t)h * NT + t) * MPAD + m] = s;
    }
    __syncthreads();  // kpT reads done; overlay kvT
    short* kvT = kpT; // [64 dv][296 m] = 37.9KB <= 41.5KB
#pragma unroll
    for (int tt = 0; tt < 5; ++tt) {
        int tr = w + tt * 4;
        if (tr < 18) {
            for (int nf = 0; nf < 4; ++nf) {
                int dv = nf * 16 + fr;
                for (int j = 0; j < 4; ++j) {
                    int m = tr * 16 + (l >> 4) * 4 + j;
                    kvT[dv * 296 + m] = f2bf(acc[tt][nf][j]);
                }
            }
        }
    }
    __syncthreads();
    // coalesced KVc store
    for (int lp = 0; lp < 9; ++lp) {
        int c = tid + lp * 256;       // 2304 = 64 dv * 36
        int dv = c / 36, c8 = c % 36;
        short8 v = *(const short8*)&kvT[dv * 296 + c8 * 8];
        *(short8*)&KVc[(((size_t)h * NT + t) * DV + dv) * MPAD + c8 * 8] = v;
    }
}

// ---------------- fused exclusive chunk-scans, batched loads (all 32 independent) ----------------
__global__ __launch_bounds__(256) void scan_kernel(const short* __restrict__ KVc,
                                                   short* __restrict__ KVbT,
                                                   float* __restrict__ Ks,
                                                   float* __restrict__ Ktot) {
    int idx = blockIdx.x * 256 + threadIdx.x;
    const int NKV = NHEAD * DV * MPAD;       // 147456
    if (idx < NKV) {
        int h = idx / (DV * MPAD);
        int rem = idx % (DV * MPAD);
        size_t base = (size_t)h * NT * DV * MPAD + rem;
        short vals[NT];
#pragma unroll
        for (int t = 0; t < NT; ++t) vals[t] = KVc[base + (size_t)t * DV * MPAD];
        float run = 0.f;
#pragma unroll
        for (int t = 0; t < NT; ++t) {
            KVbT[base + (size_t)t * DV * MPAD] = f2bf(run);
            run += bf2f(vals[t]);
        }
    } else {
        int j = idx - NKV;
        if (j < NHEAD * MPAD) {
            int h = j / MPAD, m = j % MPAD;
            size_t base = (size_t)h * NT * MPAD + m;
            float vals[NT];
#pragma unroll
            for (int t = 0; t < NT; ++t) vals[t] = Ks[base + (size_t)t * MPAD];
            float run = 0.f;
#pragma unroll
            for (int t = 0; t < NT; ++t) {
                Ks[base + (size_t)t * MPAD] = run;
                run += vals[t];
            }
            Ktot[(size_t)h * MPAD + m] = run;
        }
    }
}

// ---------------- phase C: MFMA intra+inter+denominators; grid (t, h); S^T async-staged ----------------
__global__ __launch_bounds__(256) void phasec_kernel(const short* __restrict__ qp,
                                                     const short* __restrict__ kp,
                                                     const short* __restrict__ vh,
                                                     const short* __restrict__ KVbT,
                                                     const float* __restrict__ Ks,
                                                     const float* __restrict__ Ktot,
                                                     float* __restrict__ attn) {
    int t = blockIdx.x, h = blockIdx.y;
    __shared__ short Buf[64][296];   // Kp (QK^T phase) then St (inter phase)
    __shared__ short Vt[64][72];     // [dv][i]
    __shared__ short Am[64][72];     // masked A, bf16
    __shared__ float Ksp[MPAD], Ktp[MPAD];
    __shared__ float fscale_s[64];
    int tid = threadIdx.x;
    int w = tid >> 6, l = tid & 63;
    int fr = l & 15, fq = (l >> 4) * 8;
    const short* qpb = qp + ((size_t)h * NSEQ + (size_t)t * 64) * MPAD;
    const short* kpb = kp + ((size_t)h * NSEQ + (size_t)t * 64) * MPAD;
    const short* stb = KVbT + ((size_t)h * NT + t) * DV * MPAD;

    short8 qf[9];
#pragma unroll
    for (int ks = 0; ks < 9; ++ks)
        qf[ks] = *(const short8*)&qpb[(size_t)(w * 16 + fr) * MPAD + ks * 32 + fq];

    int srow = tid >> 2, sc4 = tid & 3;
#pragma unroll
    for (int lp = 0; lp < 9; ++lp) {
        int c = sc4 + lp * 4;
        *(short8*)&Buf[srow][c * 8] = *(const short8*)&kpb[(size_t)srow * MPAD + c * 8];
    }
    // stage Vt via row reads + LDS transpose
    for (int lp = 0; lp < 2; ++lp) {
        int c = tid + lp * 256;
        int i = c & 63, d8 = (c >> 6) * 8;
        short8 v = *(const short8*)&vh[(size_t)(t * 64 + i) * DMODEL + h * DV + d8];
        for (int jj = 0; jj < 8; ++jj) Vt[d8 + jj][i] = v[jj];
    }
    for (int idx = tid; idx < MPAD; idx += 256) {
        Ksp[idx] = Ks[((size_t)h * NT + t) * MPAD + idx];
        Ktp[idx] = Ktot[(size_t)h * MPAD + idx];
    }
    // async-issue S^T loads; latency hides under QK^T MFMAs
    short8 stg[9];
#pragma unroll
    for (int lp = 0; lp < 9; ++lp) {
        int c = sc4 + lp * 4;
        stg[lp] = *(const short8*)&stb[(size_t)srow * MPAD + c * 8];
    }
    __syncthreads();

    f32x4 accA[4] = {f32x4{0,0,0,0}, f32x4{0,0,0,0}, f32x4{0,0,0,0}, f32x4{0,0,0,0}};
    f32x4 accO[4] = {f32x4{0,0,0,0}, f32x4{0,0,0,0}, f32x4{0,0,0,0}, f32x4{0,0,0,0}};
#pragma unroll 3
    for (int ks = 0; ks < 9; ++ks) {
        int ko = ks * 32 + fq;
        for (int nf = 0; nf < 4; ++nf) {
            short8 bk = *(const short8*)&Buf[nf * 16 + fr][ko];
            accA[nf] = __builtin_amdgcn_mfma_f32_16x16x32_bf16(qf[ks], bk, accA[nf], 0, 0, 0);
        }
    }
    __syncthreads();
#pragma unroll
    for (int lp = 0; lp < 9; ++lp) {
        int c = sc4 + lp * 4;
        *(short8*)&Buf[srow][c * 8] = stg[lp];
    }
    for (int nf = 0; nf < 4; ++nf) {
        int col = nf * 16 + fr;
        for (int j = 0; j < 4; ++j) {
            int row = w * 16 + (l >> 4) * 4 + j;
            Am[row][col] = (col <= row) ? f2bf(accA[nf][j]) : (short)0;
        }
    }
    __syncthreads();
#pragma unroll 3
    for (int ks = 0; ks < 9; ++ks) {
        int ko = ks * 32 + fq;
        for (int nf = 0; nf < 4; ++nf) {
            short8 bs = *(const short8*)&Buf[nf * 16 + fr][ko];
            accO[nf] = __builtin_amdgcn_mfma_f32_16x16x32_bf16(qf[ks], bs, accO[nf], 0, 0, 0);
        }
    }
#pragma unroll
    for (int ks = 0; ks < 2; ++ks) {
        int ko = ks * 32 + fq;
        short8 a = *(const short8*)&Am[w * 16 + fr][ko];
        for (int nf = 0; nf < 4; ++nf) {
            short8 b = *(const short8*)&Vt[nf * 16 + fr][ko];
            accO[nf] = __builtin_amdgcn_mfma_f32_16x16x32_bf16(a, b, accO[nf], 0, 0, 0);
        }
    }
    int di = tid >> 2, dp = tid & 3;
    float dc = 0.f, df = 0.f;
    {
        const short* amrow = &Am[di][dp * 16];
        short8 s0 = *(const short8*)amrow;
        short8 s1 = *(const short8*)(amrow + 8);
        for (int j2 = 0; j2 < 8; ++j2) dc += bf2f(s0[j2]) + bf2f(s1[j2]);
    }
#pragma unroll
    for (int c8 = 0; c8 < 9; ++c8) {
        int m = dp * 72 + c8 * 8;
        short8 qv = *(const short8*)&qpb[(size_t)di * MPAD + m];
        for (int j2 = 0; j2 < 8; ++j2) {
            float qq = bf2f(qv[j2]);
            dc += qq * Ksp[m + j2];
            df += qq * Ktp[m + j2];
        }
    }
    dc += __shfl_xor(dc, 1); dc += __shfl_xor(dc, 2);
    df += __shfl_xor(df, 1); df += __shfl_xor(df, 2);
    if (dp == 0) {
        float dst = df;
        if (fabsf(dst) <= NORM_STAB) dst += 2.f * NORM_STAB;
        fscale_s[di] = (1.f / dc) / dst;
    }
    __syncthreads();
    for (int nf = 0; nf < 4; ++nf) {
        int col = nf * 16 + fr;
        for (int j = 0; j < 4; ++j) {
            int row = w * 16 + (l >> 4) * 4 + j;
            attn[((size_t)t * 64 + row) * DMODEL + h * DV + col] = accO[nf][j] * fscale_s[row];
        }
    }
}

// ---------------- final GEMM with bias + residual ----------------
__global__ __launch_bounds__(256) void fgemm_kernel(const float* __restrict__ A,
                                                    const float* __restrict__ B,
                                                    float* __restrict__ C,
                                                    const float* __restrict__ bias,
                                                    const float* __restrict__ residual) {
    __shared__ short As[64][40];
    __shared__ short Bs[64][40];
    int bm = blockIdx.y * 64, bn = blockIdx.x * 64;
    int tid = threadIdx.x;
    int wid = tid >> 6, lane = tid & 63;
    f32x4 acc[4] = {f32x4{0,0,0,0}, f32x4{0,0,0,0}, f32x4{0,0,0,0}, f32x4{0,0,0,0}};
    int ar = tid >> 2, akq = tid & 3;
    int bkk = tid >> 3, bng = tid & 7;
    for (int k0 = 0; k0 < DMODEL; k0 += 32) {
        {
            const float* src = A + (size_t)(bm + ar) * DMODEL + k0 + akq * 8;
            f32x4 v0 = *(const f32x4*)src;
            f32x4 v1 = *(const f32x4*)(src + 4);
            short8 sv;
            for (int j = 0; j < 4; ++j) { sv[j] = f2bf(v0[j]); sv[4 + j] = f2bf(v1[j]); }
            *(short8*)&As[ar][akq * 8] = sv;
        }
        {
            const float* src = B + (size_t)(k0 + bkk) * DMODEL + bn + bng * 8;
            f32x4 v0 = *(const f32x4*)src;
            f32x4 v1 = *(const f32x4*)(src + 4);
            for (int j = 0; j < 4; ++j) {
                Bs[bng * 8 + j][bkk] = f2bf(v0[j]);
                Bs[bng * 8 + 4 + j][bkk] = f2bf(v1[j]);
            }
        }
        __syncthreads();
        int row = wid * 16 + (lane & 15);
        int koff = (lane >> 4) * 8;
        short8 a = *(const short8*)&As[row][koff];
        for (int nf = 0; nf < 4; ++nf) {
            int col = nf * 16 + (lane & 15);
            short8 b = *(const short8*)&Bs[col][koff];
            acc[nf] = __builtin_amdgcn_mfma_f32_16x16x32_bf16(a, b, acc[nf], 0, 0, 0);
        }
        __syncthreads();
    }
    for (int nf = 0; nf < 4; ++nf) {
        int col = bn + nf * 16 + (lane & 15);
        for (int j = 0; j < 4; ++j) {
            int row = bm + wid * 16 + (lane >> 4) * 4 + j;
            C[(size_t)row * DMODEL + col] =
                acc[nf][j] + bias[col] + residual[(size_t)row * DMODEL + col];
        }
    }
}

extern "C" void kernel_launch(void* const* d_in, const int* in_sizes, int n_in,
                              void* d_out, int out_size, void* d_ws, size_t ws_size,
                              hipStream_t stream) {
    const float* q = (const float*)d_in[0];
    const float* k = (const float*)d_in[1];
    const float* v = (const float*)d_in[2];
    const float* Wq = (const float*)d_in[3];
    const float* Wk = (const float*)d_in[4];
    const float* Wv = (const float*)d_in[5];
    const float* Wfc = (const float*)d_in[6];
    const float* bfc = (const float*)d_in[7];
    const float* gamma = (const float*)d_in[8];
    const float* beta = (const float*)d_in[9];
    const float* rf = (const float*)d_in[10];
    float* out = (float*)d_out;

    float* ws = (float*)d_ws;
    float* attn = ws;                                      // fp32 2048*512
    short* qh = (short*)(attn + (size_t)NSEQ * DMODEL);    // bf16 2048*512
    short* kh = qh + (size_t)NSEQ * DMODEL;                // bf16 2048*512
    short* vhb = kh + (size_t)NSEQ * DMODEL;               // bf16 2048*512
    short* qp = vhb + (size_t)NSEQ * DMODEL;               // bf16 8*2048*288
    short* kp = qp + (size_t)NHEAD * NSEQ * MPAD;          // bf16 8*2048*288
    short* KVc = kp + (size_t)NHEAD * NSEQ * MPAD;         // bf16 8*32*64*288
    short* KVbT = KVc + (size_t)NHEAD * NT * DV * MPAD;    // bf16 8*32*64*288
    float* Ks = (float*)(KVbT + (size_t)NHEAD * NT * DV * MPAD);   // fp32 8*32*288
    float* Ktot = Ks + (size_t)NHEAD * NT * MPAD;          // 8*288
    float* hk = Ktot + (size_t)NHEAD * MPAD;               // 8*2048
    float* partial = hk + (size_t)NHEAD * NSEQ;            // 256

    dim3 gq(DMODEL / 64, NSEQ / 64, 3);
    qkv_kernel<<<gq, 256, 0, stream>>>(q, k, v, Wq, Wk, Wv, gamma, beta,
                                       qh, kh, vhb, hk, partial);
    dim3 gf(NT, NHEAD, 2);
    feat_kernel<<<gf, 256, 0, stream>>>(qh, kh, rf, hk, partial, qp, kp);
    dim3 ga(NT, NHEAD);
    chunksum_kernel<<<ga, 256, 0, stream>>>(kp, vhb, KVc, Ks);
    int scan_threads = NHEAD * DV * MPAD + NHEAD * MPAD;
    scan_kernel<<<(scan_threads + 255) / 256, 256, 0, stream>>>(KVc, KVbT, Ks, Ktot);
    dim3 gc(NT, NHEAD);
    phasec_kernel<<<gc, 256, 0, stream>>>(qp, kp, vhb, KVbT, Ks, Ktot, attn);
    dim3 g(DMODEL / 64, NSEQ / 64);
    fgemm_kernel<<<g, 256, 0, stream>>>(attn, Wfc, out, bfc, q);
}